// Round 8
// baseline (795.343 us; speedup 1.0000x reference)
//
#include <hip/hip_runtime.h>
#include <stddef.h>

typedef float f32x4 __attribute__((ext_vector_type(4)));
typedef short s16x8 __attribute__((ext_vector_type(8)));
typedef unsigned long long u64;

__device__ __forceinline__ short f2bf(float f) {
    unsigned u = __float_as_uint(f);
    unsigned r = (u + 0x7fffu + ((u >> 16) & 1u)) >> 16;   // RNE
    return (short)r;
}

__device__ __forceinline__ void load_lds16(const void* g, void* l) {
    __builtin_amdgcn_global_load_lds(
        (const __attribute__((address_space(1))) unsigned int*)g,
        (__attribute__((address_space(3))) unsigned int*)l, 16, 0, 0);
}

// ---------------- bf16 MFMA GEMM: C = act(A @ W^T + bias) ------------------
// 128x128 tile, BK=64, 4 waves. Linear LDS + XOR-swizzled global source +
// swizzled ds_read (rule #21). XCD swizzle: each XCD owns a contiguous
// N-slab (B-operand slab stays resident in its private L2; A streams via L3).
// Requires nwg % 8 == 0 (all our grids: 512, 448, 224, 32).
template<bool OBF16, bool RELU>
__global__ __launch_bounds__(256)
void gemm_mfma(const short* __restrict__ A, const short* __restrict__ W,
               const float* __restrict__ bias, void* __restrict__ Cv,
               int M, int N, int K)
{
    __shared__ short As[128 * 64];
    __shared__ short Bs[128 * 64];
    const int tid = threadIdx.x;
    const int l    = tid & 63;
    const int wave = tid >> 6;
    const int wr = wave >> 1, wc = wave & 1;

    // XCD-chunked, n-major decode: XCD k gets a contiguous N-slab.
    const int nwg = gridDim.x * gridDim.y;
    const int f = blockIdx.y * gridDim.x + blockIdx.x;
    const int rank = (f & 7) * (nwg >> 3) + (f >> 3);
    const int n0 = (rank / gridDim.y) * 128;
    const int m0 = (rank % gridDim.y) * 128;

    f32x4 acc[4][4];
#pragma unroll
    for (int i = 0; i < 4; ++i)
#pragma unroll
        for (int j = 0; j < 4; ++j) {
            acc[i][j][0] = 0.f; acc[i][j][1] = 0.f;
            acc[i][j][2] = 0.f; acc[i][j][3] = 0.f;
        }

    const int srow = tid >> 3;
    const int gc   = (tid & 7) ^ (srow & 7);
    const short* gA = A + (size_t)(m0 + srow) * K + gc * 8;
    const short* gB = W + (size_t)(n0 + srow) * K + gc * 8;
    char* AsB = (char*)As;
    char* BsB = (char*)Bs;
    char* dstA = AsB + wave * 1024;
    char* dstB = BsB + wave * 1024;

    int aoff[4], boff[4], soff[2];
#pragma unroll
    for (int mi = 0; mi < 4; ++mi) aoff[mi] = (wr * 64 + mi * 16 + (l & 15)) * 128;
#pragma unroll
    for (int ni = 0; ni < 4; ++ni) boff[ni] = (wc * 64 + ni * 16 + (l & 15)) * 128;
#pragma unroll
    for (int kh = 0; kh < 2; ++kh) soff[kh] = ((kh * 4 + (l >> 4)) ^ (l & 7)) * 16;

    for (int kt = 0; kt < K; kt += 64) {
#pragma unroll
        for (int j = 0; j < 4; ++j) {
            load_lds16(gA + (size_t)j * 32 * K + kt, dstA + j * 4096);
            load_lds16(gB + (size_t)j * 32 * K + kt, dstB + j * 4096);
        }
        __syncthreads();
#pragma unroll
        for (int kh = 0; kh < 2; ++kh) {
            s16x8 af[4], bfr[4];
#pragma unroll
            for (int mi = 0; mi < 4; ++mi)
                af[mi] = *(const s16x8*)(AsB + aoff[mi] + soff[kh]);
#pragma unroll
            for (int ni = 0; ni < 4; ++ni)
                bfr[ni] = *(const s16x8*)(BsB + boff[ni] + soff[kh]);
#pragma unroll
            for (int mi = 0; mi < 4; ++mi)
#pragma unroll
                for (int ni = 0; ni < 4; ++ni)
                    acc[mi][ni] = __builtin_amdgcn_mfma_f32_16x16x32_bf16(
                        af[mi], bfr[ni], acc[mi][ni], 0, 0, 0);
        }
        __syncthreads();
    }

    const int colf = l & 15, rowf = (l >> 4) * 4;
#pragma unroll
    for (int mi = 0; mi < 4; ++mi)
#pragma unroll
        for (int ni = 0; ni < 4; ++ni) {
            const int n = n0 + wc * 64 + ni * 16 + colf;
            const float bv = bias[n];
#pragma unroll
            for (int r = 0; r < 4; ++r) {
                const int m = m0 + wr * 64 + mi * 16 + rowf + r;
                float v = acc[mi][ni][r] + bv;
                if (RELU) v = fmaxf(v, 0.f);
                if (OBF16) ((short*)Cv)[(size_t)m * N + n] = f2bf(v);
                else       ((float*)Cv)[(size_t)m * N + n] = v;
            }
        }
}

// ---------------- f32 -> bf16 conversion (optional elementwise mask) -------
__global__ void conv_bf16(const float* __restrict__ in, const float* __restrict__ mask,
                          short* __restrict__ out, int n4)
{
    int i = blockIdx.x * blockDim.x + threadIdx.x;
    if (i >= n4) return;
    float4 v = ((const float4*)in)[i];
    if (mask) {
        float4 m = ((const float4*)mask)[i];
        v.x *= m.x; v.y *= m.y; v.z *= m.z; v.w *= m.w;
    }
    short4 o;
    o.x = f2bf(v.x); o.y = f2bf(v.y); o.z = f2bf(v.z); o.w = f2bf(v.w);
    ((short4*)out)[i] = o;
}

// ---------------- f32 -> bf16 with K-padding (for GEMM1, 168 -> 192) -------
__global__ void padconv_bf16(const float* __restrict__ in, const float* __restrict__ mask,
                             short* __restrict__ out, int M, int Kin4, int Kout4)
{
    int idx = blockIdx.x * blockDim.x + threadIdx.x;
    if (idx >= M * Kout4) return;
    int m = idx / Kout4, k4 = idx % Kout4;
    float4 v = make_float4(0.f, 0.f, 0.f, 0.f);
    if (k4 < Kin4) {
        v = ((const float4*)in)[(size_t)m * Kin4 + k4];
        if (mask) {
            float4 mm = ((const float4*)mask)[(size_t)m * Kin4 + k4];
            v.x *= mm.x; v.y *= mm.y; v.z *= mm.z; v.w *= mm.w;
        }
    }
    short4 o;
    o.x = f2bf(v.x); o.y = f2bf(v.y); o.z = f2bf(v.z); o.w = f2bf(v.w);
    ((short4*)out)[(size_t)m * Kout4 + k4] = o;
}

// ---------------- combined LSTM biases -------------------------------------
__global__ void bias_sum_kernel(const float* __restrict__ bihf, const float* __restrict__ bhhf,
                                const float* __restrict__ bihb, const float* __restrict__ bhhb,
                                float* __restrict__ o)
{
    int i = blockIdx.x * blockDim.x + threadIdx.x;
    if (i < 2048)      o[i] = bihf[i] + bhhf[i];
    else if (i < 4096) o[i] = bihb[i - 2048] + bhhb[i - 2048];
}

// ---------------- persistent BiLSTM v2: all 64 steps, one launch -----------
// 128 blocks (dir x 64 jg, 8 gate-cols each), all co-resident (<=256 CUs).
// whh slice in LDS for the WHOLE sequence; c in registers. Cross-block h
// exchange + flags via agent-scope relaxed atomics ONLY (L2-bypass, no
// fences, no wbl2, no contended RMW). Arrival = own-flag store; wait =
// wave0 polls 64 flags in parallel (one lane each).
__global__ __launch_bounds__(256, 1)
void lstm_persist2(const float* __restrict__ xp,   // [2048][4096] f32
                   const short* __restrict__ whb,  // [2][2048][512] bf16
                   short* __restrict__ hbuf,       // [2][2][16384] bf16
                   short* __restrict__ y,          // [32][64][1024] bf16
                   float* __restrict__ out,        // hidden/cell at end
                   unsigned* __restrict__ flags)   // [2][64][16] u32
{
    __shared__ short wT[8 * 32 * 64];    // 32 KB: 8 k-tiles x [32 rows][64 k]
    __shared__ short hT[8 * 32 * 64];    // 32 KB
    __shared__ float gbuf[4][32][9];     // gate exchange
    __shared__ short hout[32][8];        // h_new collect

    const int bid = blockIdx.x;
    const int dir = bid >> 6;
    const int jg  = bid & 63;
    const int j0  = jg * 8;
    const int tid = threadIdx.x;
    const int l    = tid & 63;
    const int wave = tid >> 6;

    const short* whh = whb + (size_t)dir * 1048576;
    short* hb = hbuf + dir * 2 * 16384;
    unsigned* myflag  = flags + (size_t)(dir * 64 + jg) * 16;
    unsigned* dirflag = flags + (size_t)dir * 1024;

    char* wTB = (char*)wT;
    char* hTB = (char*)hT;

    // ---- stage whh slice ONCE (32 rows x 512 k), swizzled DMA ----
    {
        const int rloc = wave * 8 + (l >> 3);
        const int gc   = (l & 7) ^ (rloc & 7);
        const short* gW = whh + (size_t)((rloc >> 3) * 512 + j0 + (rloc & 7)) * 512 + gc * 8;
        char* dstW = wTB + wave * 1024;
#pragma unroll
        for (int kt = 0; kt < 8; ++kt)
            load_lds16(gW + kt * 64, dstW + kt * 4096);
    }   // drained by the first __syncthreads below

    // fragment offsets (swizzled read side)
    int soff[2];
    soff[0] = ((0 * 4 + (l >> 4)) ^ (l & 7)) * 16;
    soff[1] = ((1 * 4 + (l >> 4)) ^ (l & 7)) * 16;
    const int a0off = (l & 15) * 128;
    const int a1off = (16 + (l & 15)) * 128;
    const int bof   = (wave * 8 + (l & 7)) * 128;

    // h staging: thread -> row srow, k-tile q, 8 pieces of 16B
    const int srow = wave * 8 + (l >> 3);     // 0..31
    const int q    = l & 7;                   // k-tile 0..7
    char* hdst = hTB + q * 4096 + srow * 128;
    const int rx = srow & 7;

    // gate-math ownership: 1 output per thread
    const int gb = tid >> 3;          // batch 0..31
    const int gj = tid & 7;           // j-local 0..7
    const int j  = j0 + gj;

    float c_reg = 0.f;                // cell state in registers all 64 steps

    for (int t = 0; t < 64; ++t) {
        const int tt = dir ? (63 - t) : t;
        const short* hread  = hb + (t & 1) * 16384;
        short*       hwrite = hb + ((t + 1) & 1) * 16384;

        // xp prefetch (normal cached loads; read-only data)
        const float* xpr = xp + ((size_t)(gb * 64 + tt)) * 4096 + dir * 2048 + j;
        const float xi = xpr[0], xf = xpr[512], xg = xpr[1024], xo = xpr[1536];

        // ---- stage h: agent-scope u64 loads -> swizzled ds_write_b128 ----
        {
            const u64* hs = (const u64*)(hread + srow * 512 + q * 64);
#pragma unroll
            for (int p = 0; p < 8; ++p) {
                union { u64 w[2]; s16x8 v; } u;
                u.w[0] = __hip_atomic_load(hs + p * 2,     __ATOMIC_RELAXED, __HIP_MEMORY_SCOPE_AGENT);
                u.w[1] = __hip_atomic_load(hs + p * 2 + 1, __ATOMIC_RELAXED, __HIP_MEMORY_SCOPE_AGENT);
                *(s16x8*)(hdst + ((p ^ rx) << 4)) = u.v;
            }
        }
        __syncthreads();

        // ---- MFMA: gates[32 batches, 8 cols] for gate `wave`, K=512 ----
        f32x4 acc0, acc1;
        acc0[0] = 0.f; acc0[1] = 0.f; acc0[2] = 0.f; acc0[3] = 0.f;
        acc1 = acc0;
#pragma unroll
        for (int kt = 0; kt < 8; ++kt) {
#pragma unroll
            for (int kh = 0; kh < 2; ++kh) {
                s16x8 bv = *(const s16x8*)(wTB + kt * 4096 + bof + soff[kh]);
                s16x8 a0 = *(const s16x8*)(hTB + kt * 4096 + a0off + soff[kh]);
                s16x8 a1 = *(const s16x8*)(hTB + kt * 4096 + a1off + soff[kh]);
                acc0 = __builtin_amdgcn_mfma_f32_16x16x32_bf16(a0, bv, acc0, 0, 0, 0);
                acc1 = __builtin_amdgcn_mfma_f32_16x16x32_bf16(a1, bv, acc1, 0, 0, 0);
            }
        }

        // scatter gates: wave w = gate w; C/D col l&15 (valid < 8)
        if ((l & 15) < 8) {
            const int sj = l & 15, r4 = (l >> 4) * 4;
#pragma unroll
            for (int r = 0; r < 4; ++r) {
                gbuf[wave][r4 + r][sj]      = acc0[r];
                gbuf[wave][16 + r4 + r][sj] = acc1[r];
            }
        }
        __syncthreads();

        // fused gate math: thread (gb, gj) owns one (batch, j)
        {
            float g_i = gbuf[0][gb][gj] + xi;
            float g_f = gbuf[1][gb][gj] + xf;
            float g_g = gbuf[2][gb][gj] + xg;
            float g_o = gbuf[3][gb][gj] + xo;
            float si = 1.f / (1.f + expf(-g_i));
            float sf = 1.f / (1.f + expf(-g_f));
            float so = 1.f / (1.f + expf(-g_o));
            float tg = tanhf(g_g);
            c_reg = sf * c_reg + si * tg;
            float h_new = so * tanhf(c_reg);

            const short hb16 = f2bf(h_new);
            hout[gb][gj] = hb16;
            y[((size_t)(gb * 64 + tt)) * 1024 + dir * 512 + j] = hb16;  // cached

            if (t == 63) {
                out[524288 + dir * 16384 + gb * 512 + j]         = h_new;
                out[524288 + 32768 + dir * 16384 + gb * 512 + j] = c_reg;
            }
        }
        __syncthreads();   // hout ready; hT/gbuf safe to reuse next iter

        if (t == 63) break;

        // ---- publish h_{t+1}: wave0 packs 4 bf16 -> one agent u64 store ----
        if (tid < 64) {
            const int row = tid >> 1, seg = tid & 1;
            union { unsigned short s[4]; u64 w; } pk;
#pragma unroll
            for (int i2 = 0; i2 < 4; ++i2)
                pk.s[i2] = (unsigned short)hout[row][seg * 4 + i2];
            __hip_atomic_store((u64*)(hwrite + row * 512 + j0 + seg * 4),
                               pk.w, __ATOMIC_RELAXED, __HIP_MEMORY_SCOPE_AGENT);
        }
        // arrival: release store in the SAME wave as the h stores ->
        // its s_waitcnt vmcnt(0) orders them; no fence, no L2 flush.
        if (tid == 0)
            __hip_atomic_store(myflag, (unsigned)(t + 1),
                               __ATOMIC_RELEASE, __HIP_MEMORY_SCOPE_AGENT);
        // wait: wave0 polls all 64 flags in parallel (lane i -> flag i)
        if (tid < 64) {
            for (;;) {
                unsigned v = __hip_atomic_load(dirflag + (size_t)l * 16,
                                               __ATOMIC_RELAXED, __HIP_MEMORY_SCOPE_AGENT);
                if (__ballot(v >= (unsigned)(t + 1)) == ~0ull) break;
                __builtin_amdgcn_s_sleep(2);
            }
        }
        __syncthreads();
    }
}

// ---------------------------------------------------------------------------
extern "C" void kernel_launch(void* const* d_in, const int* in_sizes, int n_in,
                              void* d_out, int out_size, void* d_ws, size_t ws_size,
                              hipStream_t stream)
{
    const float* x     = (const float*)d_in[0];
    const float* w1    = (const float*)d_in[1];
    const float* b1    = (const float*)d_in[2];
    const float* mask1 = (const float*)d_in[3];
    const float* w2    = (const float*)d_in[4];
    const float* b2    = (const float*)d_in[5];
    const float* mask2 = (const float*)d_in[6];
    const float* wihf  = (const float*)d_in[7];
    const float* whhf  = (const float*)d_in[8];
    const float* bihf  = (const float*)d_in[9];
    const float* bhhf  = (const float*)d_in[10];
    const float* wihb  = (const float*)d_in[11];
    const float* whhb  = (const float*)d_in[12];
    const float* bihb  = (const float*)d_in[13];
    const float* bhhb  = (const float*)d_in[14];
    const float* wo1   = (const float*)d_in[15];
    const float* bo1   = (const float*)d_in[16];
    const float* wo2   = (const float*)d_in[17];
    const float* bo2   = (const float*)d_in[18];
    float* out = (float*)d_out;

    // ---- workspace regions (byte offsets), lifetime-based aliasing ----
    char* base = (char*)d_ws;
    short* wqb  = (short*)base;                       // later whb
    short* whb  = (short*)base;
    char*  Breg = base + 29360128;
    short* h2b  = (short*)Breg;
    short* xpad = (short*)Breg;                       // [2048][192] bf16
    short* w1mb = (short*)(Breg + 786432);            // [1792][192] bf16
    char*  Creg = base + 44040192;
    float* xp   = (float*)Creg;
    short* w2b  = (short*)Creg;
    char*  Dreg = base + 77594624;
    short* h1b  = (short*)Dreg;
    short* ybuf = (short*)Dreg;
    short* o1   = (short*)(Dreg + 4194304);
    short* wo1b = (short*)(Dreg + 5242880);
    short* wo2b = (short*)(Dreg + 5767168);
    char*  Ereg = base + 84934656;
    short* hbuf = (short*)Ereg;                       // 131072 B
    unsigned* flagsp = (unsigned*)(Ereg + 131072);    // 8192 B  [2][64][16] u32
    float* bsum = (float*)(Ereg + 139264);            // 16384 B

    hipMemsetAsync(Ereg, 0, 139264, stream);   // hbuf + flags zeros
    bias_sum_kernel<<<16, 256, 0, stream>>>(bihf, bhhf, bihb, bhhb, bsum);

    // weight / input conversions
    conv_bf16<<<6272, 256, 0, stream>>>(w2, mask2, w2b, 6422528 / 4);
    conv_bf16<<<7168, 256, 0, stream>>>(wihf, nullptr, wqb, 7340032 / 4);
    conv_bf16<<<7168, 256, 0, stream>>>(wihb, nullptr, wqb + 7340032, 7340032 / 4);
    padconv_bf16<<<384, 256, 0, stream>>>(x, nullptr, xpad, 2048, 42, 48);
    padconv_bf16<<<336, 256, 0, stream>>>(w1, mask1, w1mb, 1792, 42, 48);

    // GEMM1 (MFMA, K padded to 192)
    gemm_mfma<true, true><<<dim3(1792 / 128, 2048 / 128), 256, 0, stream>>>(
        xpad, w1mb, b1, h1b, 2048, 1792, 192);

    // GEMM2 (MFMA)
    gemm_mfma<true, true><<<dim3(3584 / 128, 2048 / 128), 256, 0, stream>>>(
        h1b, w2b, b2, h2b, 2048, 3584, 1792);

    // merged LSTM input projection: h2b @ [wihf;wihb]^T + bsum -> xp f32
    gemm_mfma<false, false><<<dim3(4096 / 128, 2048 / 128), 256, 0, stream>>>(
        h2b, wqb, bsum, xp, 2048, 4096, 3584);

    // recurrent weights to bf16 (aliases wqb -> after xproj)
    conv_bf16<<<1024, 256, 0, stream>>>(whhf, nullptr, whb, 1048576 / 4);
    conv_bf16<<<1024, 256, 0, stream>>>(whhb, nullptr, whb + 1048576, 1048576 / 4);
    // head weights to bf16 (alias h1b tail -> after GEMM2)
    conv_bf16<<<256, 256, 0, stream>>>(wo1, nullptr, wo1b, 262144 / 4);
    conv_bf16<<<64, 256, 0, stream>>>(wo2, nullptr, wo2b, 65536 / 4);

    // entire BiLSTM recurrence: ONE persistent kernel, 128 co-resident blocks
    lstm_persist2<<<128, 256, 0, stream>>>(xp, whb, hbuf, ybuf, out, flagsp);

    // output head (MFMA)
    gemm_mfma<true, true><<<dim3(256 / 128, 2048 / 128), 256, 0, stream>>>(
        ybuf, wo1b, bo1, o1, 2048, 256, 1024);
    gemm_mfma<false, false><<<dim3(256 / 128, 2048 / 128), 256, 0, stream>>>(
        o1, wo2b, bo2, out, 2048, 256, 256);
}

// Round 9
// 593.866 us; speedup vs baseline: 1.3393x; 1.3393x over previous
//
#include <hip/hip_runtime.h>
#include <stddef.h>

typedef float f32x4 __attribute__((ext_vector_type(4)));
typedef short s16x8 __attribute__((ext_vector_type(8)));

__device__ __forceinline__ short f2bf(float f) {
    unsigned u = __float_as_uint(f);
    unsigned r = (u + 0x7fffu + ((u >> 16) & 1u)) >> 16;   // RNE
    return (short)r;
}

__device__ __forceinline__ void load_lds16(const void* g, void* l) {
    __builtin_amdgcn_global_load_lds(
        (const __attribute__((address_space(1))) unsigned int*)g,
        (__attribute__((address_space(3))) unsigned int*)l, 16, 0, 0);
}

// ---------------- bf16 MFMA GEMM: C = act(A @ W^T + bias) ------------------
// 128x128 tile, BK=64, 4 waves. Linear LDS + XOR-swizzled global source +
// swizzled ds_read (rule #21). XCD swizzle: each XCD owns a contiguous
// N-slab (B-operand slab stays resident in its private L2; A streams via L3).
// Requires nwg % 8 == 0 (all our grids: 512, 448, 224, 32).
template<bool OBF16, bool RELU>
__global__ __launch_bounds__(256)
void gemm_mfma(const short* __restrict__ A, const short* __restrict__ W,
               const float* __restrict__ bias, void* __restrict__ Cv,
               int M, int N, int K)
{
    __shared__ short As[128 * 64];
    __shared__ short Bs[128 * 64];
    const int tid = threadIdx.x;
    const int l    = tid & 63;
    const int wave = tid >> 6;
    const int wr = wave >> 1, wc = wave & 1;

    // XCD-chunked, n-major decode: XCD k gets a contiguous N-slab.
    const int nwg = gridDim.x * gridDim.y;
    const int f = blockIdx.y * gridDim.x + blockIdx.x;
    const int rank = (f & 7) * (nwg >> 3) + (f >> 3);
    const int n0 = (rank / gridDim.y) * 128;
    const int m0 = (rank % gridDim.y) * 128;

    f32x4 acc[4][4];
#pragma unroll
    for (int i = 0; i < 4; ++i)
#pragma unroll
        for (int j = 0; j < 4; ++j) {
            acc[i][j][0] = 0.f; acc[i][j][1] = 0.f;
            acc[i][j][2] = 0.f; acc[i][j][3] = 0.f;
        }

    const int srow = tid >> 3;
    const int gc   = (tid & 7) ^ (srow & 7);
    const short* gA = A + (size_t)(m0 + srow) * K + gc * 8;
    const short* gB = W + (size_t)(n0 + srow) * K + gc * 8;
    char* AsB = (char*)As;
    char* BsB = (char*)Bs;
    char* dstA = AsB + wave * 1024;
    char* dstB = BsB + wave * 1024;

    int aoff[4], boff[4], soff[2];
#pragma unroll
    for (int mi = 0; mi < 4; ++mi) aoff[mi] = (wr * 64 + mi * 16 + (l & 15)) * 128;
#pragma unroll
    for (int ni = 0; ni < 4; ++ni) boff[ni] = (wc * 64 + ni * 16 + (l & 15)) * 128;
#pragma unroll
    for (int kh = 0; kh < 2; ++kh) soff[kh] = ((kh * 4 + (l >> 4)) ^ (l & 7)) * 16;

    for (int kt = 0; kt < K; kt += 64) {
#pragma unroll
        for (int j = 0; j < 4; ++j) {
            load_lds16(gA + (size_t)j * 32 * K + kt, dstA + j * 4096);
            load_lds16(gB + (size_t)j * 32 * K + kt, dstB + j * 4096);
        }
        __syncthreads();
#pragma unroll
        for (int kh = 0; kh < 2; ++kh) {
            s16x8 af[4], bfr[4];
#pragma unroll
            for (int mi = 0; mi < 4; ++mi)
                af[mi] = *(const s16x8*)(AsB + aoff[mi] + soff[kh]);
#pragma unroll
            for (int ni = 0; ni < 4; ++ni)
                bfr[ni] = *(const s16x8*)(BsB + boff[ni] + soff[kh]);
#pragma unroll
            for (int mi = 0; mi < 4; ++mi)
#pragma unroll
                for (int ni = 0; ni < 4; ++ni)
                    acc[mi][ni] = __builtin_amdgcn_mfma_f32_16x16x32_bf16(
                        af[mi], bfr[ni], acc[mi][ni], 0, 0, 0);
        }
        __syncthreads();
    }

    const int colf = l & 15, rowf = (l >> 4) * 4;
#pragma unroll
    for (int mi = 0; mi < 4; ++mi)
#pragma unroll
        for (int ni = 0; ni < 4; ++ni) {
            const int n = n0 + wc * 64 + ni * 16 + colf;
            const float bv = bias[n];
#pragma unroll
            for (int r = 0; r < 4; ++r) {
                const int m = m0 + wr * 64 + mi * 16 + rowf + r;
                float v = acc[mi][ni][r] + bv;
                if (RELU) v = fmaxf(v, 0.f);
                if (OBF16) ((short*)Cv)[(size_t)m * N + n] = f2bf(v);
                else       ((float*)Cv)[(size_t)m * N + n] = v;
            }
        }
}

// ---------------- fused early setup: zeros + bsum + 3 convs + 2 padconvs ---
// One flat-f4-indexed kernel replacing memset + bias_sum + 5 conv launches.
// Segments (f4 counts):
//   [0,65536)            zeros -> Ereg (hbuf bf16 + cbuf f32, bitwise 0 ok)
//   [65536,66560)        bsum  = b_ih + b_hh (fwd | bwd)
//   [66560,1672192)      w2b   = bf16(w2 * mask2)
//   [1672192,3507200)    wqb   = bf16(wihf)
//   [3507200,5342208)    wqb+  = bf16(wihb)
//   [5342208,5440512)    xpad  = bf16(x), K 42f4 -> 48f4 zero-pad
//   [5440512,5526528)    w1mb  = bf16(w1*mask1), K 42f4 -> 48f4 zero-pad
__global__ __launch_bounds__(256)
void setup_early(const float* __restrict__ x,    const float* __restrict__ w1,
                 const float* __restrict__ mask1,const float* __restrict__ w2,
                 const float* __restrict__ mask2,
                 const float* __restrict__ wihf, const float* __restrict__ wihb,
                 const float* __restrict__ bihf, const float* __restrict__ bhhf,
                 const float* __restrict__ bihb, const float* __restrict__ bhhb,
                 float4* __restrict__ zero_dst,  float* __restrict__ bsum,
                 short4* __restrict__ w2b,       short4* __restrict__ wqb,
                 short4* __restrict__ xpad,      short4* __restrict__ w1mb)
{
    int idx = blockIdx.x * blockDim.x + threadIdx.x;
    if (idx < 65536) {                                   // zeros
        zero_dst[idx] = make_float4(0.f, 0.f, 0.f, 0.f);
        return;
    }
    idx -= 65536;
    if (idx < 1024) {                                    // bsum
        float4 v;
        if (idx < 512) {
            float4 a = ((const float4*)bihf)[idx], b = ((const float4*)bhhf)[idx];
            v = make_float4(a.x + b.x, a.y + b.y, a.z + b.z, a.w + b.w);
        } else {
            float4 a = ((const float4*)bihb)[idx - 512], b = ((const float4*)bhhb)[idx - 512];
            v = make_float4(a.x + b.x, a.y + b.y, a.z + b.z, a.w + b.w);
        }
        ((float4*)bsum)[idx] = v;
        return;
    }
    idx -= 1024;
    if (idx < 1605632) {                                 // w2b (masked)
        float4 v = ((const float4*)w2)[idx];
        float4 m = ((const float4*)mask2)[idx];
        short4 o;
        o.x = f2bf(v.x * m.x); o.y = f2bf(v.y * m.y);
        o.z = f2bf(v.z * m.z); o.w = f2bf(v.w * m.w);
        w2b[idx] = o;
        return;
    }
    idx -= 1605632;
    if (idx < 3670016) {                                 // wihf | wihb -> wqb
        const float4* src = (idx < 1835008) ? (const float4*)wihf
                                            : (const float4*)wihb;
        int k = (idx < 1835008) ? idx : idx - 1835008;
        float4 v = src[k];
        short4 o;
        o.x = f2bf(v.x); o.y = f2bf(v.y); o.z = f2bf(v.z); o.w = f2bf(v.w);
        wqb[idx] = o;
        return;
    }
    idx -= 3670016;
    if (idx < 98304) {                                   // xpad (42 -> 48)
        int m = idx / 48, k4 = idx % 48;
        float4 v = make_float4(0.f, 0.f, 0.f, 0.f);
        if (k4 < 42) v = ((const float4*)x)[m * 42 + k4];
        short4 o;
        o.x = f2bf(v.x); o.y = f2bf(v.y); o.z = f2bf(v.z); o.w = f2bf(v.w);
        xpad[idx] = o;
        return;
    }
    idx -= 98304;
    if (idx < 86016) {                                   // w1mb (masked, 42->48)
        int m = idx / 48, k4 = idx % 48;
        float4 v = make_float4(0.f, 0.f, 0.f, 0.f);
        if (k4 < 42) {
            v = ((const float4*)w1)[m * 42 + k4];
            float4 mm = ((const float4*)mask1)[m * 42 + k4];
            v.x *= mm.x; v.y *= mm.y; v.z *= mm.z; v.w *= mm.w;
        }
        short4 o;
        o.x = f2bf(v.x); o.y = f2bf(v.y); o.z = f2bf(v.z); o.w = f2bf(v.w);
        w1mb[idx] = o;
    }
}

// ---------------- fused late setup: whh + head weight convs ----------------
// Must run AFTER xproj (whb aliases wqb). Segments (f4):
//   [0,262144) whhf  [262144,524288) whhb  [524288,589824) wo1  [589824,606208) wo2
__global__ __launch_bounds__(256)
void setup_late(const float* __restrict__ whhf, const float* __restrict__ whhb,
                const float* __restrict__ wo1,  const float* __restrict__ wo2,
                short4* __restrict__ whb, short4* __restrict__ wo1b,
                short4* __restrict__ wo2b)
{
    int idx = blockIdx.x * blockDim.x + threadIdx.x;
    const float4* src;
    short4* dst;
    int k;
    if (idx < 524288) {
        src = (idx < 262144) ? (const float4*)whhf : (const float4*)whhb;
        k = (idx < 262144) ? idx : idx - 262144;
        dst = whb + idx;
    } else if (idx < 589824) {
        src = (const float4*)wo1; k = idx - 524288; dst = wo1b + k;
    } else if (idx < 606208) {
        src = (const float4*)wo2; k = idx - 589824; dst = wo2b + k;
    } else return;
    float4 v = src[k];
    short4 o;
    o.x = f2bf(v.x); o.y = f2bf(v.y); o.z = f2bf(v.z); o.w = f2bf(v.w);
    *dst = o;
}

// ---------------- one BiLSTM time step, single-exposure staging ------------
// grid = 128: dir = bid>>6, jg = bid&63 -> 8 gate-cols per block, all 4 gates.
// Per step: issue ALL 16 global_load_lds per wave (8 h-tiles + 8 w-tiles),
// ONE syncthreads, 32 MFMAs, gate math. c in global f32, h ping-pong bf16.
__global__ __launch_bounds__(256, 2)
void lstm_step2(int t,
                const float* __restrict__ xp,   // [2048][4096] f32 (fwd|bwd)
                const short* __restrict__ whb,  // [2][2048][512] bf16
                short* __restrict__ hbuf,       // [2][2][32*512] bf16
                float* __restrict__ cbuf,       // [2][32*512] f32
                short* __restrict__ y,          // [32][64][1024] bf16
                float* __restrict__ out)        // hidden/cell at t==63
{
    __shared__ short wT[8 * 32 * 64];    // 32 KB: 8 k-tiles x [32 rows][64 k]
    __shared__ short hT[8 * 32 * 64];    // 32 KB
    __shared__ float gbuf[4][32][9];     // 4.6 KB gate exchange

    const int bid = blockIdx.x;
    const int dir = bid >> 6;
    const int jg  = bid & 63;
    const int j0  = jg * 8;
    const int tid = threadIdx.x;
    const int l    = tid & 63;
    const int wave = tid >> 6;
    const int tt = dir ? (63 - t) : t;

    const short* whh = whb + (size_t)dir * 1048576;
    const short* hread  = hbuf + dir * 2 * 16384 + (t & 1) * 16384;
    short*       hwrite = hbuf + dir * 2 * 16384 + ((t + 1) & 1) * 16384;
    float*       cst    = cbuf + dir * 16384;

    char* wTB = (char*)wT;
    char* hTB = (char*)hT;

    // gate-math ownership: 1 output per thread
    const int gb = tid >> 3;          // batch 0..31
    const int gj = tid & 7;           // j-local 0..7
    const int j  = j0 + gj;

    // prefetch xp + c early (independent of h staging)
    const float* xpr = xp + ((size_t)(gb * 64 + tt)) * 4096 + dir * 2048 + j;
    const float xi = xpr[0], xf = xpr[512], xg = xpr[1024], xo = xpr[1536];
    float c_old = cst[gb * 512 + j];

    // ---- staging addresses: wave w covers local rows w*8 + (l>>3) ----
    const int rloc = wave * 8 + (l >> 3);         // 0..31
    const int gc   = (l & 7) ^ (rloc & 7);        // pre-swizzled k-chunk
    // w_hh: local row r -> gate (r>>3), col j0 + (r&7)
    const short* gW = whh + (size_t)((rloc >> 3) * 512 + j0 + (rloc & 7)) * 512 + gc * 8;
    // h: local row = batch
    const short* gH = hread + rloc * 512 + gc * 8;
    char* dstW = wTB + wave * 1024;
    char* dstH = hTB + wave * 1024;

    // issue ALL staging loads, single exposure
#pragma unroll
    for (int kt = 0; kt < 8; ++kt) {
        load_lds16(gH + kt * 64, dstH + kt * 4096);
        load_lds16(gW + kt * 64, dstW + kt * 4096);
    }

    // fragment offsets (swizzled read side); B rows for cols>=8 duplicate 0..7
    int soff[2];
    soff[0] = ((0 * 4 + (l >> 4)) ^ (l & 7)) * 16;
    soff[1] = ((1 * 4 + (l >> 4)) ^ (l & 7)) * 16;
    const int a0off = (l & 15) * 128;
    const int a1off = (16 + (l & 15)) * 128;
    const int bof   = (wave * 8 + (l & 7)) * 128;   // (l&15)&7 == l&7

    __syncthreads();   // compiler inserts vmcnt(0) before barrier

    // MFMA: gates[32 batches, 8 cols] for gate `wave`, K=512
    f32x4 acc0, acc1;
    acc0[0] = 0.f; acc0[1] = 0.f; acc0[2] = 0.f; acc0[3] = 0.f;
    acc1 = acc0;
#pragma unroll
    for (int kt = 0; kt < 8; ++kt) {
#pragma unroll
        for (int kh = 0; kh < 2; ++kh) {
            s16x8 bv = *(const s16x8*)(wTB + kt * 4096 + bof + soff[kh]);
            s16x8 a0 = *(const s16x8*)(hTB + kt * 4096 + a0off + soff[kh]);
            s16x8 a1 = *(const s16x8*)(hTB + kt * 4096 + a1off + soff[kh]);
            acc0 = __builtin_amdgcn_mfma_f32_16x16x32_bf16(a0, bv, acc0, 0, 0, 0);
            acc1 = __builtin_amdgcn_mfma_f32_16x16x32_bf16(a1, bv, acc1, 0, 0, 0);
        }
    }

    // scatter gates: wave w = gate w; C/D col = l&15 (valid < 8), row batches
    if ((l & 15) < 8) {
        const int sj = l & 15, r4 = (l >> 4) * 4;
#pragma unroll
        for (int r = 0; r < 4; ++r) {
            gbuf[wave][r4 + r][sj]      = acc0[r];
            gbuf[wave][16 + r4 + r][sj] = acc1[r];
        }
    }
    __syncthreads();

    // fused gate math: thread (gb, gj) owns one (batch, j)
    {
        float g_i = gbuf[0][gb][gj] + xi;
        float g_f = gbuf[1][gb][gj] + xf;
        float g_g = gbuf[2][gb][gj] + xg;
        float g_o = gbuf[3][gb][gj] + xo;
        float si = 1.f / (1.f + expf(-g_i));
        float sf = 1.f / (1.f + expf(-g_f));
        float so = 1.f / (1.f + expf(-g_o));
        float tg = tanhf(g_g);
        float c_new = sf * c_old + si * tg;
        float h_new = so * tanhf(c_new);

        cst[gb * 512 + j] = c_new;
        const short hb16 = f2bf(h_new);
        hwrite[gb * 512 + j] = hb16;
        y[((size_t)(gb * 64 + tt)) * 1024 + dir * 512 + j] = hb16;

        if (t == 63) {
            out[524288 + dir * 16384 + gb * 512 + j]         = h_new;
            out[524288 + 32768 + dir * 16384 + gb * 512 + j] = c_new;
        }
    }
}

// ---------------------------------------------------------------------------
extern "C" void kernel_launch(void* const* d_in, const int* in_sizes, int n_in,
                              void* d_out, int out_size, void* d_ws, size_t ws_size,
                              hipStream_t stream)
{
    const float* x     = (const float*)d_in[0];
    const float* w1    = (const float*)d_in[1];
    const float* b1    = (const float*)d_in[2];
    const float* mask1 = (const float*)d_in[3];
    const float* w2    = (const float*)d_in[4];
    const float* b2    = (const float*)d_in[5];
    const float* mask2 = (const float*)d_in[6];
    const float* wihf  = (const float*)d_in[7];
    const float* whhf  = (const float*)d_in[8];
    const float* bihf  = (const float*)d_in[9];
    const float* bhhf  = (const float*)d_in[10];
    const float* wihb  = (const float*)d_in[11];
    const float* whhb  = (const float*)d_in[12];
    const float* bihb  = (const float*)d_in[13];
    const float* bhhb  = (const float*)d_in[14];
    const float* wo1   = (const float*)d_in[15];
    const float* bo1   = (const float*)d_in[16];
    const float* wo2   = (const float*)d_in[17];
    const float* bo2   = (const float*)d_in[18];
    float* out = (float*)d_out;

    // ---- workspace regions (byte offsets), lifetime-based aliasing ----
    char* base = (char*)d_ws;
    short* wqb  = (short*)base;                       // later whb
    short* whb  = (short*)base;
    char*  Breg = base + 29360128;
    short* h2b  = (short*)Breg;
    short* xpad = (short*)Breg;                       // [2048][192] bf16
    short* w1mb = (short*)(Breg + 786432);            // [1792][192] bf16
    char*  Creg = base + 44040192;
    float* xp   = (float*)Creg;
    short* w2b  = (short*)Creg;
    char*  Dreg = base + 77594624;
    short* h1b  = (short*)Dreg;
    short* ybuf = (short*)Dreg;
    short* o1   = (short*)(Dreg + 4194304);
    short* wo1b = (short*)(Dreg + 5242880);
    short* wo2b = (short*)(Dreg + 5767168);
    char*  Ereg = base + 84934656;
    short* hbuf = (short*)Ereg;                       // 131072 B
    float* cbuf = (float*)(Ereg + 131072);            // 131072 B
    float* bsum = (float*)(Ereg + 262144);            // 16384 B

    // fused setup: zeros(hbuf+cbuf) + bsum + w2b + wihf/wihb + xpad + w1mb
    setup_early<<<(5526528 + 255) / 256, 256, 0, stream>>>(
        x, w1, mask1, w2, mask2, wihf, wihb, bihf, bhhf, bihb, bhhb,
        (float4*)Ereg, bsum, (short4*)w2b, (short4*)wqb,
        (short4*)xpad, (short4*)w1mb);

    // GEMM1 (MFMA, K padded to 192)
    gemm_mfma<true, true><<<dim3(1792 / 128, 2048 / 128), 256, 0, stream>>>(
        xpad, w1mb, b1, h1b, 2048, 1792, 192);

    // GEMM2 (MFMA)
    gemm_mfma<true, true><<<dim3(3584 / 128, 2048 / 128), 256, 0, stream>>>(
        h1b, w2b, b2, h2b, 2048, 3584, 1792);

    // merged LSTM input projection: h2b @ [wihf;wihb]^T + bsum -> xp f32
    gemm_mfma<false, false><<<dim3(4096 / 128, 2048 / 128), 256, 0, stream>>>(
        h2b, wqb, bsum, xp, 2048, 4096, 3584);

    // fused late setup (after xproj: whb aliases wqb; wo* alias h1b tail)
    setup_late<<<(606208 + 255) / 256, 256, 0, stream>>>(
        whhf, whhb, wo1, wo2, (short4*)whb, (short4*)wo1b, (short4*)wo2b);

    // 64 sequential BiLSTM steps (single-exposure staging, 128 blocks)
    for (int t = 0; t < 64; ++t)
        lstm_step2<<<128, 256, 0, stream>>>(t, xp, whb, hbuf, cbuf, ybuf, out);

    // output head (MFMA)
    gemm_mfma<true, true><<<dim3(256 / 128, 2048 / 128), 256, 0, stream>>>(
        ybuf, wo1b, bo1, o1, 2048, 256, 1024);
    gemm_mfma<false, false><<<dim3(256 / 128, 2048 / 128), 256, 0, stream>>>(
        o1, wo2b, bo2, out, 2048, 256, 256);
}